// Round 1
// baseline (3734.618 us; speedup 1.0000x reference)
//
#include <hip/hip_runtime.h>

// WaveNet: B=4, T=8192, C=64 res channels, SK=256 skip, OUT=256, 16 blocks
#define NB    16
#define C     64
#define C2    128   // 2*C
#define SK    256
#define OUTC  256
#define B     4
#define T     8192
#define TT    64    // time tile for block kernel
#define TT2   32    // time tile for head kernel

// ---------------------------------------------------------------------------
// out0[b,c,t] = embed[x[b,t], c]
__global__ __launch_bounds__(256) void embed_kernel(
    const int* __restrict__ x, const float* __restrict__ embed,
    float* __restrict__ out)
{
    int idx = blockIdx.x * 256 + threadIdx.x;   // over B*C*T
    int t = idx % T;
    int c = (idx / T) % C;
    int b = idx / (T * C);
    int xi = x[b * T + t];
    out[idx] = embed[xi * C + c];
}

// ---------------------------------------------------------------------------
// One WaveNet block:
//   g = dilated_causal_conv(out_in, w_conv) + h_i           [2C]
//   z = tanh(g[:C]) * sigmoid(g[C:])
//   skip (+)= w_skip @ z ;  out_next = out_in + w_res @ z
__global__ __launch_bounds__(256) void block_kernel(
    const float* __restrict__ out_in,    // [B][C][T]
    float* __restrict__ out_next,        // [B][C][T] (unused when last)
    const float* __restrict__ h,         // [B][NB*2C][T]
    const float* __restrict__ w_conv,    // this block: [2C][C][2]
    const float* __restrict__ w_res,     // this block: [C][C]
    const float* __restrict__ w_skip,    // this block: [SK][C]
    float* __restrict__ skip,            // [B][SK][T]
    int block_idx, int dil, int first, int last)
{
    __shared__ float xt[C][TT + 128];    // input tile + max halo (dil<=128)
    __shared__ float zb[C][TT];

    const int b   = blockIdx.y;
    const int t0  = blockIdx.x * TT;
    const int tid = threadIdx.x;

    // ---- stage input tile (with dilation halo) into LDS -------------------
    const int ncols = TT + dil;          // cols t0-dil .. t0+TT-1
    for (int idx = tid; idx < C * ncols; idx += 256) {
        int j = idx % ncols;
        int c = idx / ncols;
        int g = t0 - dil + j;
        xt[c][j] = (g >= 0) ? out_in[((size_t)b * C + c) * T + g] : 0.0f;
    }
    __syncthreads();

    // ---- gated activation: z ----------------------------------------------
    const float* hb = h + ((size_t)b * NB * C2 + (size_t)block_idx * C2) * T + t0;
    for (int idx = tid; idx < C * TT; idx += 256) {
        int t = idx & (TT - 1);
        int c = idx >> 6;                // wave-uniform (64 lanes share c)
        float ga = hb[(size_t)c * T + t];
        float gb = hb[(size_t)(c + C) * T + t];
        const float* wa = w_conv + (size_t)(c)      * C * 2;
        const float* wb = w_conv + (size_t)(c + C)  * C * 2;
#pragma unroll
        for (int ic = 0; ic < C; ++ic) {
            float xm = xt[ic][t];        // x[t0+t-dil]
            float xc = xt[ic][t + dil];  // x[t0+t]
            ga += wa[ic * 2] * xm + wa[ic * 2 + 1] * xc;
            gb += wb[ic * 2] * xm + wb[ic * 2 + 1] * xc;
        }
        float zt = tanhf(ga);
        float zs = 1.0f / (1.0f + __expf(-gb));
        zb[c][t] = zt * zs;
    }
    __syncthreads();

    // ---- skip contribution: skip (+)= w_skip @ z --------------------------
    for (int idx = tid; idx < SK * TT; idx += 256) {
        int t = idx & (TT - 1);
        int o = idx >> 6;
        const float* wr = w_skip + (size_t)o * C;
        float s = 0.f;
#pragma unroll
        for (int ic = 0; ic < C; ++ic) s += wr[ic] * zb[ic][t];
        size_t oi = ((size_t)b * SK + o) * T + t0 + t;
        skip[oi] = first ? s : (skip[oi] + s);
    }

    // ---- residual: out_next = out_in + w_res @ z --------------------------
    if (!last) {
        for (int idx = tid; idx < C * TT; idx += 256) {
            int t = idx & (TT - 1);
            int o = idx >> 6;
            const float* wr = w_res + (size_t)o * C;
            float s = 0.f;
#pragma unroll
            for (int ic = 0; ic < C; ++ic) s += wr[ic] * zb[ic][t];
            size_t oi = ((size_t)b * C + o) * T + t0 + t;
            out_next[oi] = xt[o][t + dil] + s;   // xt holds out_in[t0+t]
        }
    }
}

// ---------------------------------------------------------------------------
// head: y = relu(skip); y2 = relu(w_out1 @ y); out = w_out2 @ y2
__global__ __launch_bounds__(256) void head_kernel(
    const float* __restrict__ skip, const float* __restrict__ w1,
    const float* __restrict__ w2, float* __restrict__ out)
{
    __shared__ float y [SK][TT2];
    __shared__ float y2[OUTC][TT2];

    const int b   = blockIdx.y;
    const int t0  = blockIdx.x * TT2;
    const int tid = threadIdx.x;

    for (int idx = tid; idx < SK * TT2; idx += 256) {
        int t = idx & (TT2 - 1);
        int s = idx >> 5;
        float v = skip[((size_t)b * SK + s) * T + t0 + t];
        y[s][t] = fmaxf(v, 0.f);
    }
    __syncthreads();

    for (int idx = tid; idx < OUTC * TT2; idx += 256) {
        int t = idx & (TT2 - 1);
        int o = idx >> 5;
        const float* wr = w1 + (size_t)o * SK;
        float acc = 0.f;
#pragma unroll 8
        for (int s2 = 0; s2 < SK; ++s2) acc += wr[s2] * y[s2][t];
        y2[o][t] = fmaxf(acc, 0.f);
    }
    __syncthreads();

    for (int idx = tid; idx < OUTC * TT2; idx += 256) {
        int t = idx & (TT2 - 1);
        int o = idx >> 5;
        const float* wr = w2 + (size_t)o * OUTC;
        float acc = 0.f;
#pragma unroll 8
        for (int o2 = 0; o2 < OUTC; ++o2) acc += wr[o2] * y2[o2][t];
        out[((size_t)b * OUTC + o) * T + t0 + t] = acc;
    }
}

// ---------------------------------------------------------------------------
extern "C" void kernel_launch(void* const* d_in, const int* in_sizes, int n_in,
                              void* d_out, int out_size, void* d_ws, size_t ws_size,
                              hipStream_t stream)
{
    const int*   x      = (const int*)  d_in[0];
    const float* h      = (const float*)d_in[1];
    const float* embed  = (const float*)d_in[2];
    const float* w_conv = (const float*)d_in[3];
    const float* w_res  = (const float*)d_in[4];
    const float* w_skip = (const float*)d_in[5];
    const float* w_out1 = (const float*)d_in[6];
    const float* w_out2 = (const float*)d_in[7];
    float* out = (float*)d_out;

    float* buf0 = (float*)d_ws;                       // [B][C][T]   8 MB
    float* buf1 = buf0 + (size_t)B * C * T;           // [B][C][T]   8 MB
    float* skip = buf1 + (size_t)B * C * T;           // [B][SK][T] 32 MB

    embed_kernel<<<dim3((B * C * T) / 256), 256, 0, stream>>>(x, embed, buf0);

    float* bufs[2] = {buf0, buf1};
    static const int dils[NB] = {1, 2, 4, 8, 16, 32, 64, 128,
                                 1, 2, 4, 8, 16, 32, 64, 128};
    for (int i = 0; i < NB; ++i) {
        const float* in  = bufs[i & 1];
        float*       onx = bufs[(i + 1) & 1];
        block_kernel<<<dim3(T / TT, B), 256, 0, stream>>>(
            in, onx, h,
            w_conv + (size_t)i * C2 * C * 2,
            w_res  + (size_t)i * C * C,
            w_skip + (size_t)i * SK * C,
            skip, i, dils[i], i == 0, i == NB - 1);
    }

    head_kernel<<<dim3(T / TT2, B), 256, 0, stream>>>(skip, w_out1, w_out2, out);
}

// Round 2
// 628.824 us; speedup vs baseline: 5.9390x; 5.9390x over previous
//
#include <hip/hip_runtime.h>

#define NB 16
#define Cc 64
#define TT 8192
#define Bb 4

typedef __attribute__((ext_vector_type(8))) short short8;
typedef __attribute__((ext_vector_type(16))) float f32x16;

__device__ __forceinline__ unsigned short bf16_rn(float f) {
  unsigned int u = __float_as_uint(f);
  u += 0x7FFF + ((u >> 16) & 1);
  return (unsigned short)(u >> 16);
}
__device__ __forceinline__ float bf16_to_f(unsigned short s) {
  return __uint_as_float(((unsigned int)s) << 16);
}
// staging: true-k (within 16-chunk) -> stored position
__device__ __forceinline__ int kpos(int k) {  // k in [0,16)
  int g = (k >> 2) & 1;
  int e = (k & 3) + 4 * (k >> 3);
  return g * 8 + e;
}

// ---------------------------------------------------------------------------
// weights fp32 -> bf16, k-dim permuted into frag-ready order (inverse of kpos)
__global__ __launch_bounds__(256) void cvt_permute(
    const float* __restrict__ src, short* __restrict__ dst, int n)
{
  int i = blockIdx.x * 256 + threadIdx.x;
  if (i >= n) return;
  int p = i & 15, g = p >> 3, e = p & 7;
  int k = (e & 3) + 4 * g + 8 * (e >> 2);
  int si = (i & ~15) | k;
  dst[i] = (short)bf16_rn(src[si]);
}

// resid0[b][t][c] = embed[x[b][t]][c]
__global__ __launch_bounds__(256) void embed_kernel(
    const int* __restrict__ x, const float* __restrict__ embed,
    float* __restrict__ resid)
{
  int idx = blockIdx.x * 256 + threadIdx.x;  // over B*T*C
  int c = idx & 63, bt = idx >> 6;
  resid[idx] = embed[(size_t)x[bt] * 64 + c];
}

// ---------------------------------------------------------------------------
// One WaveNet block, MFMA. resid layout [B][T][C] fp32. TTB=128, 8 waves.
__global__ __launch_bounds__(512) void block_kernel(
    const float* __restrict__ resid_in, float* __restrict__ resid_out,
    const float* __restrict__ h, const short* __restrict__ wconv,
    const short* __restrict__ wres, const short* __restrict__ wsk,
    unsigned short* __restrict__ skip,
    int blk, int dil, int first, int last)
{
  __shared__ short x_lds[128 * 128];  // [t][p(k=2ic+tap)] swizzled, 32KB
  __shared__ short z_lds[128 * 64];   // [t][p(ic)]        swizzled, 16KB

  const int b = blockIdx.y;
  const int t0 = blockIdx.x * 128;
  const int tid = threadIdx.x;
  const int lane = tid & 63;
  const int wv = tid >> 6;
  const int l31 = lane & 31;
  const int hi = lane >> 5;

  // ---- stage x tile: k=2ic -> x[t-dil][ic], k=2ic+1 -> x[t][ic] ----
  const float* rb = resid_in + (size_t)b * TT * Cc;
  for (int it = 0; it < 16; ++it) {
    int u = it * 512 + tid;           // u32 slot over 128 rows x 64
    int ic = u & 63, t = u >> 6;
    int gt = t0 + t;
    float xm = (gt - dil >= 0) ? rb[(size_t)(gt - dil) * Cc + ic] : 0.f;
    float xc = rb[(size_t)gt * Cc + ic];
    unsigned int v = (unsigned int)bf16_rn(xm) | ((unsigned int)bf16_rn(xc) << 16);
    int k = 2 * ic;
    int p = (k & ~15) | kpos(k & 15);
    unsigned int byte = (unsigned int)(t * 256 + p * 2) ^ (unsigned int)((t & 7) << 4);
    *(unsigned int*)((char*)x_lds + byte) = v;
  }

  // ---- conv acc init from h (exact fp32 add of h) ----
  const int pr = wv >> 2;  // channel-pair tile (tanh rows 32pr.., sig +64)
  const int nt = wv & 3;   // time tile
  const int tloc = nt * 32 + l31;
  const int tcol = t0 + tloc;
  f32x16 acc_a, acc_s;
  const float* hb = h + ((size_t)b * (NB * 128) + (size_t)blk * 128) * TT;
#pragma unroll
  for (int r = 0; r < 16; ++r) {
    int row = (r & 3) + 4 * hi + 8 * (r >> 2) + 32 * pr;  // 0..63
    acc_a[r] = hb[(size_t)row * TT + tcol];
    acc_s[r] = hb[(size_t)(row + 64) * TT + tcol];
  }
  __syncthreads();

  // ---- conv GEMM: g[oc][t], K=128 ----
  const short* wca = wconv + blk * 16384 + (32 * pr + l31) * 128;
  const short* wcs = wca + 64 * 128;
#pragma unroll
  for (int ks = 0; ks < 8; ++ks) {
    int off = ks * 16 + 8 * hi;
    unsigned int byte = (unsigned int)(tloc * 256 + off * 2) ^ (unsigned int)((tloc & 7) << 4);
    short8 bx = *(const short8*)((char*)x_lds + byte);
    short8 aa = *(const short8*)(wca + off);
    short8 as = *(const short8*)(wcs + off);
    acc_a = __builtin_amdgcn_mfma_f32_32x32x16_bf16(aa, bx, acc_a, 0, 0, 0);
    acc_s = __builtin_amdgcn_mfma_f32_32x32x16_bf16(as, bx, acc_s, 0, 0, 0);
  }

  // ---- gated activation, z -> LDS (bf16, packed pairs) ----
#pragma unroll
  for (int r = 0; r < 16; r += 2) {
    int ic0 = (r & 3) + 4 * hi + 8 * (r >> 2) + 32 * pr;  // even
    float ea0 = __expf(2.f * acc_a[r]);
    float z0 = (1.f - 2.f / (ea0 + 1.f)) * (1.f / (1.f + __expf(-acc_s[r])));
    float ea1 = __expf(2.f * acc_a[r + 1]);
    float z1 = (1.f - 2.f / (ea1 + 1.f)) * (1.f / (1.f + __expf(-acc_s[r + 1])));
    unsigned int v = (unsigned int)bf16_rn(z0) | ((unsigned int)bf16_rn(z1) << 16);
    int p = (ic0 & ~15) | kpos(ic0 & 15);
    unsigned int byte = (unsigned int)(tloc * 128 + p * 2) ^ (unsigned int)((tloc & 7) << 4);
    *(unsigned int*)((char*)z_lds + byte) = v;
  }
  __syncthreads();

  // ---- residual GEMM (m=t, n=oc): out = resid_in + w_res @ z ----
  if (!last) {
    const int mt = wv >> 1;
    const int ntr = wv & 1;
    const int trow = mt * 32 + l31;
    f32x16 ar;
#pragma unroll
    for (int r = 0; r < 16; ++r) ar[r] = 0.f;
    const short* wrb = wres + blk * 4096 + (ntr * 32 + l31) * 64;
#pragma unroll
    for (int ks = 0; ks < 4; ++ks) {
      int off = ks * 16 + 8 * hi;
      unsigned int byte = (unsigned int)(trow * 128 + off * 2) ^ (unsigned int)((trow & 7) << 4);
      short8 az = *(const short8*)((char*)z_lds + byte);
      short8 bw = *(const short8*)(wrb + off);
      ar = __builtin_amdgcn_mfma_f32_32x32x16_bf16(az, bw, ar, 0, 0, 0);
    }
    float* ro = resid_out + (size_t)b * TT * Cc;
#pragma unroll
    for (int r = 0; r < 16; ++r) {
      int t = mt * 32 + (r & 3) + 4 * hi + 8 * (r >> 2);
      int oc = ntr * 32 + l31;
      size_t idx = (size_t)(t0 + t) * Cc + oc;
      ro[idx] = rb[idx] + ar[r];
    }
  }

  // ---- skip GEMM (m=t, n=sk): skip (+)= w_skip @ z, bf16 accum buffer ----
  const int sk = wv * 32 + l31;
  const short* wsb = wsk + blk * 16384 + sk * 64;
  unsigned short* sp = skip + (size_t)b * TT * 256;
  for (int mt2 = 0; mt2 < 4; ++mt2) {
    const int trow = mt2 * 32 + l31;
    f32x16 as2;
#pragma unroll
    for (int r = 0; r < 16; ++r) as2[r] = 0.f;
#pragma unroll
    for (int ks = 0; ks < 4; ++ks) {
      int off = ks * 16 + 8 * hi;
      unsigned int byte = (unsigned int)(trow * 128 + off * 2) ^ (unsigned int)((trow & 7) << 4);
      short8 az = *(const short8*)((char*)z_lds + byte);
      short8 bw = *(const short8*)(wsb + off);
      as2 = __builtin_amdgcn_mfma_f32_32x32x16_bf16(az, bw, as2, 0, 0, 0);
    }
#pragma unroll
    for (int r = 0; r < 16; ++r) {
      int t = mt2 * 32 + (r & 3) + 4 * hi + 8 * (r >> 2);
      size_t idx = (size_t)(t0 + t) * 256 + sk;
      float v = as2[r];
      if (!first) v += bf16_to_f(sp[idx]);
      sp[idx] = bf16_rn(v);
    }
  }
}

// ---------------------------------------------------------------------------
// head: y=relu(skip); y2=relu(w1@y); out=w2@y2. TTB=64, 8 waves.
__global__ __launch_bounds__(512) void head_kernel(
    const unsigned short* __restrict__ skip,
    const short* __restrict__ w1, const short* __restrict__ w2,
    float* __restrict__ out)
{
  __shared__ short y_lds[64 * 256];   // 32KB
  __shared__ short y2_lds[64 * 256];  // 32KB

  const int b = blockIdx.y;
  const int t0 = blockIdx.x * 64;
  const int tid = threadIdx.x;
  const int lane = tid & 63, wv = tid >> 6;
  const int l31 = lane & 31, hi = lane >> 5;

  // stage y = relu(skip), bf16 relu = sign-bit test
  const unsigned short* sp = skip + (size_t)b * TT * 256;
  for (int it = 0; it < 16; ++it) {
    int u = it * 512 + tid;
    int kp = u & 127, t = u >> 7;
    unsigned int v = *(const unsigned int*)(sp + (size_t)(t0 + t) * 256 + kp * 2);
    unsigned int lo = (v & 0x8000u) ? 0u : (v & 0xFFFFu);
    unsigned int hh = (v & 0x80000000u) ? 0u : (v & 0xFFFF0000u);
    v = lo | hh;
    int k = kp * 2;
    int p = (k & ~15) | kpos(k & 15);
    unsigned int byte = (unsigned int)(t * 512 + p * 2) ^ (unsigned int)((t & 7) << 4);
    *(unsigned int*)((char*)y_lds + byte) = v;
  }
  __syncthreads();

  // y2 = relu(w1 @ y), transposed write to y2_lds[t][o]
  const short* w1r = w1 + (wv * 32 + l31) * 256;
  for (int ntile = 0; ntile < 2; ++ntile) {
    const int trow = ntile * 32 + l31;
    f32x16 acc;
#pragma unroll
    for (int r = 0; r < 16; ++r) acc[r] = 0.f;
#pragma unroll
    for (int ks = 0; ks < 16; ++ks) {
      int off = ks * 16 + 8 * hi;
      unsigned int byte = (unsigned int)(trow * 512 + off * 2) ^ (unsigned int)((trow & 7) << 4);
      short8 by = *(const short8*)((char*)y_lds + byte);
      short8 aw = *(const short8*)(w1r + off);
      acc = __builtin_amdgcn_mfma_f32_32x32x16_bf16(aw, by, acc, 0, 0, 0);
    }
#pragma unroll
    for (int r = 0; r < 16; r += 2) {
      int o0 = wv * 32 + (r & 3) + 4 * hi + 8 * (r >> 2);  // even
      float v0 = fmaxf(acc[r], 0.f), v1 = fmaxf(acc[r + 1], 0.f);
      unsigned int v = (unsigned int)bf16_rn(v0) | ((unsigned int)bf16_rn(v1) << 16);
      int p = (o0 & ~15) | kpos(o0 & 15);
      unsigned int byte = (unsigned int)(trow * 512 + p * 2) ^ (unsigned int)((trow & 7) << 4);
      *(unsigned int*)((char*)y2_lds + byte) = v;
    }
  }
  __syncthreads();

  // out = w2 @ y2, coalesced [B][OUT][T] write
  const short* w2r = w2 + (wv * 32 + l31) * 256;
  float* ob = out + (size_t)b * 256 * TT;
  for (int ntile = 0; ntile < 2; ++ntile) {
    const int trow = ntile * 32 + l31;
    f32x16 acc;
#pragma unroll
    for (int r = 0; r < 16; ++r) acc[r] = 0.f;
#pragma unroll
    for (int ks = 0; ks < 16; ++ks) {
      int off = ks * 16 + 8 * hi;
      unsigned int byte = (unsigned int)(trow * 512 + off * 2) ^ (unsigned int)((trow & 7) << 4);
      short8 by = *(const short8*)((char*)y2_lds + byte);
      short8 aw = *(const short8*)(w2r + off);
      acc = __builtin_amdgcn_mfma_f32_32x32x16_bf16(aw, by, acc, 0, 0, 0);
    }
#pragma unroll
    for (int r = 0; r < 16; ++r) {
      int oc = wv * 32 + (r & 3) + 4 * hi + 8 * (r >> 2);
      int t = t0 + ntile * 32 + l31;
      ob[(size_t)oc * TT + t] = acc[r];
    }
  }
}

// ---------------------------------------------------------------------------
extern "C" void kernel_launch(void* const* d_in, const int* in_sizes, int n_in,
                              void* d_out, int out_size, void* d_ws, size_t ws_size,
                              hipStream_t stream)
{
  const int* x = (const int*)d_in[0];
  const float* h = (const float*)d_in[1];
  const float* embed = (const float*)d_in[2];
  const float* w_conv = (const float*)d_in[3];
  const float* w_res = (const float*)d_in[4];
  const float* w_skip = (const float*)d_in[5];
  const float* w_out1 = (const float*)d_in[6];
  const float* w_out2 = (const float*)d_in[7];
  float* out = (float*)d_out;

  char* ws = (char*)d_ws;
  float* resid0 = (float*)ws;                                  // 8 MB
  float* resid1 = (float*)(ws + (size_t)(8 << 20));            // 8 MB
  unsigned short* skip = (unsigned short*)(ws + (size_t)(16 << 20)); // 16 MB
  short* wconvb = (short*)(ws + (size_t)(32 << 20));           // 512 KB
  short* wresb = wconvb + 262144;                              // 128 KB
  short* wskb = wresb + 65536;                                 // 512 KB
  short* w1b = wskb + 262144;                                  // 128 KB
  short* w2b = w1b + 65536;                                    // 128 KB

  cvt_permute<<<1024, 256, 0, stream>>>(w_conv, wconvb, 262144);
  cvt_permute<<<256, 256, 0, stream>>>(w_res, wresb, 65536);
  cvt_permute<<<1024, 256, 0, stream>>>(w_skip, wskb, 262144);
  cvt_permute<<<256, 256, 0, stream>>>(w_out1, w1b, 65536);
  cvt_permute<<<256, 256, 0, stream>>>(w_out2, w2b, 65536);

  embed_kernel<<<8192, 256, 0, stream>>>(x, embed, resid0);

  float* bufs[2] = {resid0, resid1};
  const int dils[NB] = {1, 2, 4, 8, 16, 32, 64, 128,
                        1, 2, 4, 8, 16, 32, 64, 128};
  for (int i = 0; i < NB; ++i) {
    block_kernel<<<dim3(64, 4), 512, 0, stream>>>(
        bufs[i & 1], bufs[(i + 1) & 1], h,
        wconvb, wresb, wskb, skip, i, dils[i], i == 0, i == NB - 1);
  }

  head_kernel<<<dim3(128, 4), 512, 0, stream>>>(skip, w1b, w2b, out);
}

// Round 4
// 406.461 us; speedup vs baseline: 9.1881x; 1.5471x over previous
//
#include <hip/hip_runtime.h>

#define NB 16
#define TT 8192
#define Bb 4

typedef __attribute__((ext_vector_type(8))) short short8;
typedef __attribute__((ext_vector_type(16))) float f32x16;

__device__ __forceinline__ unsigned short bf16_rn(float f) {
  unsigned int u = __float_as_uint(f);
  u += 0x7FFF + ((u >> 16) & 1);
  return (unsigned short)(u >> 16);
}
// within-16-chunk k -> stored position (must match on A and B operands)
__device__ __forceinline__ int kpos(int k) {
  int g = (k >> 2) & 1;
  int e = (k & 3) + 4 * (k >> 3);
  return g * 8 + e;
}
__device__ __forceinline__ int kinv(int p) {
  int g = p >> 3, e = p & 7;
  return (e & 3) + 4 * g + 8 * (e >> 2);
}

// ---------------------------------------------------------------------------
// All weights fp32 -> bf16, k-permuted. One launch.
// dwc: [blk][tap][oc(128)][icp(64)]  <- w_conv[blk][oc][ic][tap]
// dwr/dws/dw1/dw2: generic innermost-k permute.
__global__ __launch_bounds__(256) void prep_weights(
    const float* __restrict__ wconv, const float* __restrict__ wres,
    const float* __restrict__ wsk, const float* __restrict__ w1,
    const float* __restrict__ w2, short* __restrict__ dwc,
    short* __restrict__ dwr, short* __restrict__ dws,
    short* __restrict__ dw1, short* __restrict__ dw2)
{
  int i = blockIdx.x * 256 + threadIdx.x;
  if (i < 262144) {
    int k = kinv(i & 15);
    int ic = (i & 48) | k;
    int oc = (i >> 6) & 127;
    int tap = (i >> 13) & 1;
    int blk = i >> 14;
    dwc[i] = (short)bf16_rn(wconv[(((blk * 128 + oc) * 64 + ic) << 1) | tap]);
    return;
  }
  int j = i - 262144;
  if (j < 65536) { dwr[j] = (short)bf16_rn(wres[(j & ~15) | kinv(j & 15)]); return; }
  j -= 65536;
  if (j < 262144) { dws[j] = (short)bf16_rn(wsk[(j & ~15) | kinv(j & 15)]); return; }
  j -= 262144;
  if (j < 65536) { dw1[j] = (short)bf16_rn(w1[(j & ~15) | kinv(j & 15)]); return; }
  j -= 65536;
  if (j < 65536) { dw2[j] = (short)bf16_rn(w2[(j & ~15) | kinv(j & 15)]); return; }
}

// ---------------------------------------------------------------------------
// resid fp32 [b][t][c] + bf16 k-permuted copy [b][t][cp]
__global__ __launch_bounds__(256) void embed_kernel(
    const int* __restrict__ x, const float* __restrict__ embed,
    float* __restrict__ resid, unsigned short* __restrict__ r16)
{
  int idx = blockIdx.x * 256 + threadIdx.x;  // B*T*64
  int c = idx & 63, bt = idx >> 6;
  float v = embed[(size_t)x[bt] * 64 + c];
  resid[idx] = v;
  r16[(bt << 6) | (c & 48) | kpos(c & 15)] = bf16_rn(v);
}

// ---------------------------------------------------------------------------
// One WaveNet block. TTB=64, 256 threads (4 waves), grid (T/64, B).
__global__ __launch_bounds__(256) void block_kernel(
    const float* __restrict__ rin, const unsigned short* __restrict__ rin16,
    float* __restrict__ rout, unsigned short* __restrict__ rout16,
    const float* __restrict__ h, const short* __restrict__ wc,
    const short* __restrict__ wr, unsigned short* __restrict__ zg,
    int blk, int dil, int last)
{
  __shared__ short win[192 * 64];  // rows t0-128 .. t0+63, [w][icp] swizzled, 24KB
  __shared__ short zl[64 * 64];    // [t][icp] swizzled, 8KB

  const int b = blockIdx.y;
  const int t0 = blockIdx.x * 64;
  const int tid = threadIdx.x;
  const int lane = tid & 63, wv = tid >> 6;
  const int l31 = lane & 31, hi = lane >> 5;

  // ---- stage window (single bf16 read of resid copy) ----
  const unsigned short* rb16 = rin16 + (size_t)b * TT * 64;
#pragma unroll
  for (int it = 0; it < 6; ++it) {
    int u = it * 256 + tid;          // over 192 rows x 8 groups(8ch)
    int q = u & 7, w = u >> 3;
    int gt = t0 - 128 + w;
    short8 v = {};
    if (gt >= 0) v = *(const short8*)(rb16 + (size_t)gt * 64 + q * 8);
    unsigned int byte = (unsigned int)(w * 128 + q * 16) ^ (unsigned int)((w & 7) << 4);
    *(short8*)((char*)win + byte) = v;
  }

  // ---- conv acc init from h (fp32 exact) ----
  const int pr = wv >> 1, nt = wv & 1;
  const int tloc = nt * 32 + l31, tcol = t0 + tloc;
  f32x16 aA, aS;
  const float* hb = h + ((size_t)b * 2048 + (size_t)blk * 128) * TT;
#pragma unroll
  for (int r = 0; r < 16; ++r) {
    int row = (r & 3) + 4 * hi + 8 * (r >> 2) + 32 * pr;  // tanh oc 0..63
    aA[r] = hb[(size_t)row * TT + tcol];
    aS[r] = hb[(size_t)(row + 64) * TT + tcol];
  }
  __syncthreads();

  // ---- conv: two K=64 tap GEMMs on the same window ----
  const short* wA0 = wc + ((size_t)blk * 2 + 0) * 8192 + (32 * pr + l31) * 64;  // tap0
  const short* wA1 = wc + ((size_t)blk * 2 + 1) * 8192 + (32 * pr + l31) * 64;  // tap1
  const int r1 = tloc + 128;        // x[t]
  const int r0 = tloc + 128 - dil;  // x[t-dil]
#pragma unroll
  for (int ks = 0; ks < 4; ++ks) {
    int off = ks * 16 + 8 * hi;
    short8 b1 = *(const short8*)((char*)win +
        ((unsigned int)(r1 * 128 + off * 2) ^ (unsigned int)((r1 & 7) << 4)));
    short8 b0 = *(const short8*)((char*)win +
        ((unsigned int)(r0 * 128 + off * 2) ^ (unsigned int)((r0 & 7) << 4)));
    short8 a0t = *(const short8*)(wA0 + off);
    short8 a1t = *(const short8*)(wA1 + off);
    short8 a0s = *(const short8*)(wA0 + 4096 + off);   // +64 rows
    short8 a1s = *(const short8*)(wA1 + 4096 + off);
    aA = __builtin_amdgcn_mfma_f32_32x32x16_bf16(a0t, b0, aA, 0, 0, 0);
    aA = __builtin_amdgcn_mfma_f32_32x32x16_bf16(a1t, b1, aA, 0, 0, 0);
    aS = __builtin_amdgcn_mfma_f32_32x32x16_bf16(a0s, b0, aS, 0, 0, 0);
    aS = __builtin_amdgcn_mfma_f32_32x32x16_bf16(a1s, b1, aS, 0, 0, 0);
  }

  // ---- gated activation -> z_lds (packed bf16 pairs) ----
#pragma unroll
  for (int r = 0; r < 16; r += 2) {
    int ic0 = (r & 3) + 4 * hi + 8 * (r >> 2) + 32 * pr;  // even
    float z0 = (1.f - 2.f / (__expf(2.f * aA[r]) + 1.f)) *
               (1.f / (1.f + __expf(-aS[r])));
    float z1 = (1.f - 2.f / (__expf(2.f * aA[r + 1]) + 1.f)) *
               (1.f / (1.f + __expf(-aS[r + 1])));
    unsigned int v = (unsigned int)bf16_rn(z0) | ((unsigned int)bf16_rn(z1) << 16);
    int p = (ic0 & ~15) | kpos(ic0 & 15);
    unsigned int byte = (unsigned int)(tloc * 128 + p * 2) ^ (unsigned int)((tloc & 7) << 4);
    *(unsigned int*)((char*)zl + byte) = v;
  }
  __syncthreads();

  // ---- residual GEMM: rout = rin + z @ w_res^T (D[row=t][col=oc]) ----
  if (!last) {
    const int mt = wv >> 1, ntr = wv & 1;
    const int trow = mt * 32 + l31;
    f32x16 ar = {};
    const short* wrb = wr + (size_t)blk * 4096 + (ntr * 32 + l31) * 64;
#pragma unroll
    for (int ks = 0; ks < 4; ++ks) {
      int off = ks * 16 + 8 * hi;
      short8 az = *(const short8*)((char*)zl +
          ((unsigned int)(trow * 128 + off * 2) ^ (unsigned int)((trow & 7) << 4)));
      short8 bw = *(const short8*)(wrb + off);
      ar = __builtin_amdgcn_mfma_f32_32x32x16_bf16(az, bw, ar, 0, 0, 0);
    }
    const float* rbase = rin + (size_t)b * TT * 64;
    float* obase = rout + (size_t)b * TT * 64;
    unsigned short* o16 = rout16 + (size_t)b * TT * 64;
    int oc = ntr * 32 + l31;
    int ocp = (oc & 48) | kpos(oc & 15);
#pragma unroll
    for (int r = 0; r < 16; ++r) {
      int t = t0 + mt * 32 + (r & 3) + 4 * hi + 8 * (r >> 2);
      size_t idx = (size_t)t * 64 + oc;
      float v = rbase[idx] + ar[r];
      obase[idx] = v;
      o16[(size_t)t * 64 + ocp] = bf16_rn(v);
    }
  }

  // ---- z -> global (coalesced u32 from LDS) ----
  unsigned short* zb = zg + ((size_t)(blk * Bb + b) * TT + t0) * 64;
#pragma unroll
  for (int it = 0; it < 8; ++it) {
    int u = it * 256 + tid;          // 64 rows x 32 u32
    int p2 = u & 31, t = u >> 5;
    unsigned int byte = (unsigned int)(t * 128 + p2 * 4) ^ (unsigned int)((t & 7) << 4);
    unsigned int v = *(const unsigned int*)((char*)zl + byte);
    *(unsigned int*)(zb + (size_t)t * 64 + p2 * 2) = v;
  }
}

// ---------------------------------------------------------------------------
// head: skip = sum_blk wsk_blk @ z_blk (K=1024, fp32 accum); y=relu;
// y2=relu(w1@y); out=w2@y2.  TTB=64, 512 threads, grid (T/64, B).
__global__ __launch_bounds__(512) void head_kernel(
    const unsigned short* __restrict__ zg, const short* __restrict__ wsk,
    const short* __restrict__ w1, const short* __restrict__ w2,
    float* __restrict__ out)
{
  __shared__ short zbuf[2][64 * 64];  // double-buffered z chunk, 2x8KB
  __shared__ short y_lds[64 * 256];   // [t][skp], 32KB
  __shared__ short y2_lds[64 * 256];  // [t][op],  32KB

  const int b = blockIdx.y;
  const int t0 = blockIdx.x * 64;
  const int tid = threadIdx.x;
  const int lane = tid & 63, wv = tid >> 6;
  const int l31 = lane & 31, hi = lane >> 5;

  // prologue: stage z chunk for blk 0
  {
    int u = tid;                     // 64x32 u32 over 512 threads -> 4 its
#pragma unroll
    for (int it = 0; it < 4; ++it, u += 512) {
      int p2 = u & 31, t = u >> 5;
      unsigned int v = *(const unsigned int*)(zg + ((size_t)(0 * Bb + b) * TT + t0 + t) * 64 + p2 * 2);
      unsigned int byte = (unsigned int)(t * 128 + p2 * 4) ^ (unsigned int)((t & 7) << 4);
      *(unsigned int*)((char*)zbuf[0] + byte) = v;
    }
  }

  f32x16 acc0 = {}, acc1 = {};       // D[row=t(mt)][col=sk=wv*32+l31]
  const short* wsb = wsk + (wv * 32 + l31) * 64;

  for (int blk = 0; blk < NB; ++blk) {
    __syncthreads();
    if (blk < NB - 1) {
      int u = tid;
#pragma unroll
      for (int it = 0; it < 4; ++it, u += 512) {
        int p2 = u & 31, t = u >> 5;
        unsigned int v = *(const unsigned int*)(zg +
            ((size_t)((blk + 1) * Bb + b) * TT + t0 + t) * 64 + p2 * 2);
        unsigned int byte = (unsigned int)(t * 128 + p2 * 4) ^ (unsigned int)((t & 7) << 4);
        *(unsigned int*)((char*)zbuf[(blk + 1) & 1] + byte) = v;
      }
    }
    const short* zb = zbuf[blk & 1];
    const short* wb = wsb + (size_t)blk * 16384;
#pragma unroll
    for (int ks = 0; ks < 4; ++ks) {
      int off = ks * 16 + 8 * hi;
      short8 bw = *(const short8*)(wb + off);
      short8 az0 = *(const short8*)((char*)zb +
          ((unsigned int)(l31 * 128 + off * 2) ^ (unsigned int)((l31 & 7) << 4)));
      short8 az1 = *(const short8*)((char*)zb +
          ((unsigned int)((32 + l31) * 128 + off * 2) ^ (unsigned int)(((32 + l31) & 7) << 4)));
      acc0 = __builtin_amdgcn_mfma_f32_32x32x16_bf16(az0, bw, acc0, 0, 0, 0);
      acc1 = __builtin_amdgcn_mfma_f32_32x32x16_bf16(az1, bw, acc1, 0, 0, 0);
    }
  }

  // relu -> y_lds[t][skp]   (FIX: sk is 8-bit -> keep bits 4-7 with &0xF0)
  {
    int sk = wv * 32 + l31;
    int p = (sk & 0xF0) | kpos(sk & 15);
#pragma unroll
    for (int r = 0; r < 16; ++r) {
      int dt = (r & 3) + 4 * hi + 8 * (r >> 2);
      unsigned int b0 = (unsigned int)(dt * 512 + p * 2) ^ (unsigned int)((dt & 7) << 4);
      *(short*)((char*)y_lds + b0) = (short)bf16_rn(fmaxf(acc0[r], 0.f));
      int dt1 = dt + 32;
      unsigned int b1 = (unsigned int)(dt1 * 512 + p * 2) ^ (unsigned int)((dt1 & 7) << 4);
      *(short*)((char*)y_lds + b1) = (short)bf16_rn(fmaxf(acc1[r], 0.f));
    }
  }
  __syncthreads();

  // y2 = relu(w1 @ y): D[row=o][col=t], write transposed y2_lds[t][op]
  const short* w1r = w1 + (wv * 32 + l31) * 256;
#pragma unroll
  for (int ntile = 0; ntile < 2; ++ntile) {
    const int trow = ntile * 32 + l31;
    f32x16 acc = {};
#pragma unroll
    for (int ks = 0; ks < 16; ++ks) {
      int off = ks * 16 + 8 * hi;
      short8 by = *(const short8*)((char*)y_lds +
          ((unsigned int)(trow * 512 + off * 2) ^ (unsigned int)((trow & 7) << 4)));
      short8 aw = *(const short8*)(w1r + off);
      acc = __builtin_amdgcn_mfma_f32_32x32x16_bf16(aw, by, acc, 0, 0, 0);
    }
#pragma unroll
    for (int r = 0; r < 16; r += 2) {
      int o0 = wv * 32 + (r & 3) + 4 * hi + 8 * (r >> 2);
      unsigned int v = (unsigned int)bf16_rn(fmaxf(acc[r], 0.f)) |
                       ((unsigned int)bf16_rn(fmaxf(acc[r + 1], 0.f)) << 16);
      int p = (o0 & ~15) | kpos(o0 & 15);
      unsigned int byte = (unsigned int)(trow * 512 + p * 2) ^ (unsigned int)((trow & 7) << 4);
      *(unsigned int*)((char*)y2_lds + byte) = v;
    }
  }
  __syncthreads();

  // out = w2 @ y2: D[row=oc][col=t], coalesced [B][OUT][T] write
  const short* w2r = w2 + (wv * 32 + l31) * 256;
  float* ob = out + (size_t)b * 256 * TT;
#pragma unroll
  for (int ntile = 0; ntile < 2; ++ntile) {
    const int trow = ntile * 32 + l31;
    f32x16 acc = {};
#pragma unroll
    for (int ks = 0; ks < 16; ++ks) {
      int off = ks * 16 + 8 * hi;
      short8 by = *(const short8*)((char*)y2_lds +
          ((unsigned int)(trow * 512 + off * 2) ^ (unsigned int)((trow & 7) << 4)));
      short8 aw = *(const short8*)(w2r + off);
      acc = __builtin_amdgcn_mfma_f32_32x32x16_bf16(aw, by, acc, 0, 0, 0);
    }
#pragma unroll
    for (int r = 0; r < 16; ++r) {
      int oc = wv * 32 + (r & 3) + 4 * hi + 8 * (r >> 2);
      ob[(size_t)oc * TT + t0 + trow] = acc[r];
    }
  }
}

// ---------------------------------------------------------------------------
extern "C" void kernel_launch(void* const* d_in, const int* in_sizes, int n_in,
                              void* d_out, int out_size, void* d_ws, size_t ws_size,
                              hipStream_t stream)
{
  const int* x = (const int*)d_in[0];
  const float* h = (const float*)d_in[1];
  const float* embed = (const float*)d_in[2];
  const float* w_conv = (const float*)d_in[3];
  const float* w_res = (const float*)d_in[4];
  const float* w_skip = (const float*)d_in[5];
  const float* w_out1 = (const float*)d_in[6];
  const float* w_out2 = (const float*)d_in[7];
  float* out = (float*)d_out;

  char* ws = (char*)d_ws;
  float* resid0 = (float*)ws;                                   // 8 MB
  float* resid1 = (float*)(ws + (size_t)(8 << 20));             // 8 MB
  unsigned short* r16_0 = (unsigned short*)(ws + (size_t)(16 << 20));  // 4 MB
  unsigned short* r16_1 = (unsigned short*)(ws + (size_t)(20 << 20));  // 4 MB
  unsigned short* zg = (unsigned short*)(ws + (size_t)(24 << 20));     // 64 MB
  short* dwc = (short*)(ws + (size_t)(88 << 20));               // 512 KB
  short* dwr = dwc + 262144;                                    // 128 KB
  short* dws = dwr + 65536;                                     // 512 KB
  short* dw1 = dws + 262144;                                    // 128 KB
  short* dw2 = dw1 + 65536;                                     // 128 KB

  prep_weights<<<2816, 256, 0, stream>>>(w_conv, w_res, w_skip, w_out1, w_out2,
                                         dwc, dwr, dws, dw1, dw2);
  embed_kernel<<<8192, 256, 0, stream>>>(x, embed, resid0, r16_0);

  float* rf[2] = {resid0, resid1};
  unsigned short* rh[2] = {r16_0, r16_1};
  const int dils[NB] = {1, 2, 4, 8, 16, 32, 64, 128,
                        1, 2, 4, 8, 16, 32, 64, 128};
  for (int i = 0; i < NB; ++i) {
    block_kernel<<<dim3(TT / 64, Bb), 256, 0, stream>>>(
        rf[i & 1], rh[i & 1], rf[(i + 1) & 1], rh[(i + 1) & 1],
        h, dwc, dwr, zg, i, dils[i], i == NB - 1);
  }

  head_kernel<<<dim3(TT / 64, Bb), 512, 0, stream>>>(zg, dws, dw1, dw2, out);
}